// Round 8
// baseline (515.807 us; speedup 1.0000x reference)
//
#include <hip/hip_runtime.h>
#include <type_traits>

#define HID 256
#define PTS 64
typedef unsigned short ushort_t;
typedef unsigned int uint_t;
typedef __attribute__((ext_vector_type(8))) _Float16 half8v;   // 8 fp16 = 4 VGPR
typedef __attribute__((ext_vector_type(2))) __fp16 pk16x2;     // cvt_pkrtz result type
typedef __attribute__((ext_vector_type(4))) float f32x4;
typedef __attribute__((ext_vector_type(16))) float f32x16;

#define LO_SCALE   4096.0f          // 2^12
#define LO_INV     0.000244140625f  // 2^-12

// activation: m = layer % 4 : 0 sin, 1 cos, 2 gaussian, 3 tanh
template <int M>
__device__ __forceinline__ float act(float z) {
    if constexpr (M == 0) return __sinf(z);
    else if constexpr (M == 1) return __cosf(z);
    else if constexpr (M == 2) return __expf(-z * z);
    else { float e = __expf(2.0f * z); return 1.0f - 2.0f / (e + 1.0f); }
}

// truncation split: vh32 = v with mantissa cut to fp16 width (exact), residual scaled
__device__ __forceinline__ float trunc16(float v) {
    return __builtin_bit_cast(float, __builtin_bit_cast(uint_t, v) & 0xFFFFE000u);
}
// pack two floats to fp16x2 bits (RTZ; exact for pre-truncated values)
__device__ __forceinline__ uint_t pkrtz(float a, float b) {
    pk16x2 r = __builtin_amdgcn_cvt_pkrtz(a, b);
    return __builtin_bit_cast(uint_t, r);
}

// =====================================================================
// Weight prep for 32x32x16 A-fragments (W as the A operand: row=j, K=k).
// frag f = (L*16 + ks)*8 + jt ; lane l, elem e ->
//   W[L][ks*16 + (l>>5)*8 + e][jt*32 + (l&31)]
// stored at (f*64 + l)*8 + e  (lane-contiguous 16B).
// =====================================================================
#define NFRAG (9 * 16 * 8)          // 1152 frags
#define PREP_THREADS (NFRAG * 64)   // 73728

__global__ void prep_w(const float* __restrict__ Ws,
                       _Float16* __restrict__ WHI, _Float16* __restrict__ WLO) {
    int t = blockIdx.x * 256 + threadIdx.x;
    if (t >= PREP_THREADS) return;
    int l  = t & 63;
    int f  = t >> 6;            // 0..1151
    int jt = f & 7;
    int ks = (f >> 3) & 15;
    int L  = f >> 7;            // 0..8
    int j  = jt * 32 + (l & 31);
    int kb = ks * 16 + (l >> 5) * 8;
    const float* Wp = Ws + (size_t)L * 65536;
    _Float16* oh = WHI + (size_t)t * 8;
    _Float16* ol = WLO + (size_t)t * 8;
    #pragma unroll
    for (int e = 0; e < 8; ++e) {
        float wv = Wp[(size_t)(kb + e) * 256 + j];
        float hi32 = trunc16(wv);
        oh[e] = (_Float16)hi32;                           // exact
        ol[e] = (_Float16)((wv - hi32) * LO_SCALE);       // scaled lo
    }
}

// =====================================================================
// Main fused kernel: 512 threads = 8 waves, 64 points/block.
// LDS h as [p][k] fp16 hi / scaled-lo, XOR-swizzle elem = p*256 + (k ^ ((p&7)<<3)).
// SWAPPED operands: C^T = mfma_32x32x16(W-frag, h-frag):
//   wave w owns j-slice jt=w (32 j) x all 64 p (2 p-tiles of 32).
//   C: col(lane&31)=p, row=(reg&3)+8*(reg>>2)+4*(lane>>5)=j  -> per thread
//   runs of 4 consecutive j for ONE p  -> packed b64 LDS writes.
// Split-fp16: acc += Whi*hhi ; accL += Whi*hlo' + Wlo'*hhi (2^12 scale)
// z = acc + accL*2^-12.
// =====================================================================
__global__ __launch_bounds__(512, 4) void cppn_mfma(
    const float* __restrict__ x,    // (N,12)
    const float* __restrict__ W0,   // (12,256)
    const float* __restrict__ b0,   // (256,)
    const float* __restrict__ bs,   // (9,256)
    const float* __restrict__ Wout, // (256,3)
    const float* __restrict__ bout, // (3,)
    const _Float16* __restrict__ WHI,
    const _Float16* __restrict__ WLO,
    float* __restrict__ out,        // (N,3)
    int n)
{
    __shared__ ushort_t ha[64 * 256];   // 32 KB hi
    __shared__ ushort_t hb[64 * 256];   // 32 KB lo (scaled)

    const int tid = threadIdx.x;
    const int l   = tid & 63;
    const int w   = tid >> 6;           // wave 0..7
    const long p0 = (long)blockIdx.x * PTS;

    // ---------------- layer 0 (fp32): point p=l, cols [w*32, w*32+32) ----
    {
        const int p  = l;
        const long pg = p0 + p;
        float xv[12];
        if (pg < n) {
            const float4* xr = (const float4*)(x + pg * 12);
            float4 a = xr[0], b = xr[1], c = xr[2];
            xv[0]=a.x; xv[1]=a.y; xv[2]=a.z;  xv[3]=a.w;
            xv[4]=b.x; xv[5]=b.y; xv[6]=b.z;  xv[7]=b.w;
            xv[8]=c.x; xv[9]=c.y; xv[10]=c.z; xv[11]=c.w;
        } else {
            #pragma unroll
            for (int k = 0; k < 12; ++k) xv[k] = 0.0f;
        }
        const int jb = w * 32;
        float z[32];
        #pragma unroll
        for (int jj = 0; jj < 32; ++jj) z[jj] = b0[jb + jj];
        #pragma unroll
        for (int k = 0; k < 12; ++k) {
            const float a = xv[k];
            #pragma unroll
            for (int jj = 0; jj < 32; ++jj)
                z[jj] = fmaf(a, W0[k * HID + jb + jj], z[jj]);
        }
        const int swz = (p & 7) << 3;
        #pragma unroll
        for (int jj = 0; jj < 32; jj += 2) {
            float v0 = act<0>(z[jj]), v1 = act<0>(z[jj + 1]);
            float t0 = trunc16(v0), t1 = trunc16(v1);
            uint_t ph = pkrtz(t0, t1);                    // exact for truncated vals
            uint_t pl = pkrtz((v0 - t0) * LO_SCALE, (v1 - t1) * LO_SCALE);
            int ei = p * 256 + ((jb + jj) ^ swz);         // even -> 4B aligned
            *(uint_t*)&ha[ei] = ph;
            *(uint_t*)&hb[ei] = pl;
        }
    }
    __syncthreads();

    // ---------------- layers 1..9: split-fp16 32x32x16 MFMA ------------
    const int lm5  = l & 31;
    const int hi5  = l >> 5;
    const int aswz = (l & 7) << 3;      // (p&7)<<3 for p = pt*32+lm5
    const int rowb[2] = { (0 * 32 + lm5) * 256, (1 * 32 + lm5) * 256 };

    for (int Li = 0; Li < 9; ++Li) {
        // A-frag (W) base for this layer & wave: frag index (Li*16+ks)*8 + w
        const _Float16* __restrict__ WH = WHI + ((size_t)(Li * 128 + w) * 64 + (size_t)l) * 8;
        const _Float16* __restrict__ WL = WLO + ((size_t)(Li * 128 + w) * 64 + (size_t)l) * 8;
        // per-ks stride: 8 frags * 512 elems = 4096

        f32x16 acc[2], accL[2];
        #pragma unroll
        for (int pt = 0; pt < 2; ++pt) {
            #pragma unroll
            for (int r = 0; r < 16; ++r) { acc[pt][r] = 0.f; accL[pt][r] = 0.f; }
        }

        half8v ah = *(const half8v*)(WH);
        half8v al = *(const half8v*)(WL);

        #pragma unroll 1
        for (int ks = 0; ks < 16; ++ks) {
            const int ksn = (ks + 1) & 15;          // ks=15 redundantly reloads 0
            half8v ahn = *(const half8v*)(WH + (size_t)ksn * 4096);
            half8v aln = *(const half8v*)(WL + (size_t)ksn * 4096);

            const int ke = (ks * 16 + hi5 * 8) ^ aswz;
            half8v bh0 = *(const half8v*)&ha[rowb[0] + ke];
            half8v bl0 = *(const half8v*)&hb[rowb[0] + ke];
            half8v bh1 = *(const half8v*)&ha[rowb[1] + ke];
            half8v bl1 = *(const half8v*)&hb[rowb[1] + ke];

            acc[0]  = __builtin_amdgcn_mfma_f32_32x32x16_f16(ah, bh0, acc[0],  0, 0, 0);
            acc[1]  = __builtin_amdgcn_mfma_f32_32x32x16_f16(ah, bh1, acc[1],  0, 0, 0);
            accL[0] = __builtin_amdgcn_mfma_f32_32x32x16_f16(ah, bl0, accL[0], 0, 0, 0);
            accL[1] = __builtin_amdgcn_mfma_f32_32x32x16_f16(ah, bl1, accL[1], 0, 0, 0);
            accL[0] = __builtin_amdgcn_mfma_f32_32x32x16_f16(al, bh0, accL[0], 0, 0, 0);
            accL[1] = __builtin_amdgcn_mfma_f32_32x32x16_f16(al, bh1, accL[1], 0, 0, 0);

            ah = ahn; al = aln;
        }
        __syncthreads();   // all LDS reads of this layer done

        const float* bsL = bs + Li * 256;
        const int m = (Li + 1) & 3;
        auto storeact = [&](auto mt) {
            constexpr int M = decltype(mt)::value;
            #pragma unroll
            for (int d = 0; d < 4; ++d) {
                // j-run of 4: j = w*32 + d*8 + hi5*4 + c  (c=0..3, reg r = d*4+c)
                const int jrun = w * 32 + d * 8 + hi5 * 4;
                float4 b4 = *(const float4*)(bsL + jrun);
                #pragma unroll
                for (int pt = 0; pt < 2; ++pt) {
                    float v[4], th[4];
                    #pragma unroll
                    for (int c = 0; c < 4; ++c) {
                        const int r = d * 4 + c;
                        float bj = (c == 0) ? b4.x : (c == 1) ? b4.y : (c == 2) ? b4.z : b4.w;
                        float zv = acc[pt][r] + accL[pt][r] * LO_INV + bj;
                        v[c]  = act<M>(zv);
                        th[c] = trunc16(v[c]);
                    }
                    uint2 uh = make_uint2(pkrtz(th[0], th[1]), pkrtz(th[2], th[3]));
                    uint2 ul = make_uint2(pkrtz((v[0]-th[0])*LO_SCALE, (v[1]-th[1])*LO_SCALE),
                                          pkrtz((v[2]-th[2])*LO_SCALE, (v[3]-th[3])*LO_SCALE));
                    const int p  = pt * 32 + lm5;
                    const int ei = p * 256 + (jrun ^ aswz);   // 4-elem run, 8B aligned
                    *(uint2*)&ha[ei] = uh;
                    *(uint2*)&hb[ei] = ul;
                }
            }
        };
        if      (m == 0) storeact(std::integral_constant<int,0>{});
        else if (m == 1) storeact(std::integral_constant<int,1>{});
        else if (m == 2) storeact(std::integral_constant<int,2>{});
        else             storeact(std::integral_constant<int,3>{});
        __syncthreads();
    }

    // ---------------- output: h @ Wout + bout, sigmoid ------------------
    if (tid < 192) {
        const int p = tid & 63;
        const int c = tid >> 6;             // 0..2 (wave-uniform)
        const long pg = p0 + p;
        if (pg < n) {
            const int swz = (p & 7) << 3;
            float zacc = bout[c];
            #pragma unroll 4
            for (int c2 = 0; c2 < 32; ++c2) {
                const int ei = p * 256 + ((c2 * 8) ^ swz);
                half8v vh = *(const half8v*)&ha[ei];
                half8v vl = *(const half8v*)&hb[ei];
                #pragma unroll
                for (int e = 0; e < 8; ++e) {
                    const int k = c2 * 8 + e;
                    float hv = (float)vh[e] + (float)vl[e] * LO_INV;
                    zacc = fmaf(hv, Wout[k * 3 + c], zacc);
                }
            }
            out[pg * 3 + c] = 1.0f / (1.0f + __expf(-zacc));
        }
    }
}

// =====================================================================
// Fallback (fp32, R2 structure) if ws too small for the split weights.
// =====================================================================
__global__ __launch_bounds__(512, 4) void cppn_fused_fp32(
    const float* __restrict__ x, const float* __restrict__ W0,
    const float* __restrict__ b0, const float* __restrict__ Ws,
    const float* __restrict__ bs, const float* __restrict__ Wout,
    const float* __restrict__ bout, float* __restrict__ out, int n)
{
    __shared__ float h[HID][PTS];
    const int tid  = threadIdx.x;
    const int p    = tid & 63;
    const int j0   = __builtin_amdgcn_readfirstlane((tid >> 6) << 5);
    const long pg  = (long)blockIdx.x * PTS + p;
    const bool live = (pg < n);
    {
        float xv[12];
        if (live) {
            const float4* xr = (const float4*)(x + pg * 12);
            float4 a = xr[0], b = xr[1], c = xr[2];
            xv[0]=a.x; xv[1]=a.y; xv[2]=a.z;  xv[3]=a.w;
            xv[4]=b.x; xv[5]=b.y; xv[6]=b.z;  xv[7]=b.w;
            xv[8]=c.x; xv[9]=c.y; xv[10]=c.z; xv[11]=c.w;
        } else {
            #pragma unroll
            for (int k = 0; k < 12; ++k) xv[k] = 0.0f;
        }
        float acc[32];
        #pragma unroll
        for (int q = 0; q < 32; ++q) acc[q] = 0.0f;
        #pragma unroll
        for (int k = 0; k < 12; ++k) {
            const float a = xv[k];
            const float4* wr = (const float4*)(W0 + k * HID + j0);
            #pragma unroll
            for (int q = 0; q < 8; ++q) {
                float4 wv = wr[q];
                acc[4*q+0] = fmaf(a, wv.x, acc[4*q+0]);
                acc[4*q+1] = fmaf(a, wv.y, acc[4*q+1]);
                acc[4*q+2] = fmaf(a, wv.z, acc[4*q+2]);
                acc[4*q+3] = fmaf(a, wv.w, acc[4*q+3]);
            }
        }
        #pragma unroll
        for (int q = 0; q < 8; ++q) {
            float4 b4 = *(const float4*)(b0 + j0 + 4*q);
            h[j0+4*q+0][p] = act<0>(acc[4*q+0] + b4.x);
            h[j0+4*q+1][p] = act<0>(acc[4*q+1] + b4.y);
            h[j0+4*q+2][p] = act<0>(acc[4*q+2] + b4.z);
            h[j0+4*q+3][p] = act<0>(acc[4*q+3] + b4.w);
        }
        __syncthreads();
    }
    auto layerF = [&](const float* __restrict__ W, const float* __restrict__ b, auto mtag) {
        constexpr int M = decltype(mtag)::value;
        float acc[32];
        #pragma unroll
        for (int q = 0; q < 32; ++q) acc[q] = 0.0f;
        #pragma unroll 2
        for (int k = 0; k < HID; ++k) {
            const float a = h[k][p];
            const float4* wr = (const float4*)(W + k * HID + j0);
            #pragma unroll
            for (int q = 0; q < 8; ++q) {
                float4 wv = wr[q];
                acc[4*q+0] = fmaf(a, wv.x, acc[4*q+0]);
                acc[4*q+1] = fmaf(a, wv.y, acc[4*q+1]);
                acc[4*q+2] = fmaf(a, wv.z, acc[4*q+2]);
                acc[4*q+3] = fmaf(a, wv.w, acc[4*q+3]);
            }
        }
        __syncthreads();
        #pragma unroll
        for (int q = 0; q < 8; ++q) {
            float4 b4 = *(const float4*)(b + j0 + 4*q);
            h[j0+4*q+0][p] = act<M>(acc[4*q+0] + b4.x);
            h[j0+4*q+1][p] = act<M>(acc[4*q+1] + b4.y);
            h[j0+4*q+2][p] = act<M>(acc[4*q+2] + b4.z);
            h[j0+4*q+3][p] = act<M>(acc[4*q+3] + b4.w);
        }
        __syncthreads();
    };
    layerF(Ws + 0*65536, bs + 0*256, std::integral_constant<int,1>{});
    layerF(Ws + 1*65536, bs + 1*256, std::integral_constant<int,2>{});
    layerF(Ws + 2*65536, bs + 2*256, std::integral_constant<int,3>{});
    layerF(Ws + 3*65536, bs + 3*256, std::integral_constant<int,0>{});
    layerF(Ws + 4*65536, bs + 4*256, std::integral_constant<int,1>{});
    layerF(Ws + 5*65536, bs + 5*256, std::integral_constant<int,2>{});
    layerF(Ws + 6*65536, bs + 6*256, std::integral_constant<int,3>{});
    layerF(Ws + 7*65536, bs + 7*256, std::integral_constant<int,0>{});
    layerF(Ws + 8*65536, bs + 8*256, std::integral_constant<int,1>{});
    if (tid < 192) {
        const int pp = tid & 63;
        const int c  = tid >> 6;
        const long pgo = (long)blockIdx.x * PTS + pp;
        if (pgo < n) {
            float z = bout[c];
            #pragma unroll 4
            for (int k = 0; k < HID; ++k)
                z = fmaf(h[k][pp], Wout[k * 3 + c], z);
            out[pgo * 3 + c] = 1.0f / (1.0f + __expf(-z));
        }
    }
}

extern "C" void kernel_launch(void* const* d_in, const int* in_sizes, int n_in,
                              void* d_out, int out_size, void* d_ws, size_t ws_size,
                              hipStream_t stream) {
    const float* x    = (const float*)d_in[0];
    const float* W0   = (const float*)d_in[1];
    const float* b0   = (const float*)d_in[2];
    const float* Ws   = (const float*)d_in[3];
    const float* bs   = (const float*)d_in[4];
    const float* Wout = (const float*)d_in[5];
    const float* bout = (const float*)d_in[6];
    float* out = (float*)d_out;

    const int n = in_sizes[0] / 12;
    const int grid = (n + PTS - 1) / PTS;

    const size_t whi_bytes = (size_t)PREP_THREADS * 8 * sizeof(_Float16); // 1,179,648
    const size_t need = 2 * whi_bytes;

    if (ws_size >= need) {
        _Float16* WHI = (_Float16*)d_ws;
        _Float16* WLO = (_Float16*)((char*)d_ws + whi_bytes);
        prep_w<<<(PREP_THREADS + 255) / 256, 256, 0, stream>>>(Ws, WHI, WLO);
        cppn_mfma<<<grid, 512, 0, stream>>>(x, W0, b0, bs, Wout, bout, WHI, WLO, out, n);
    } else {
        cppn_fused_fp32<<<grid, 512, 0, stream>>>(x, W0, b0, Ws, bs, Wout, bout, out, n);
    }
}